// Round 13
// baseline (118.874 us; speedup 1.0000x reference)
//
#include <hip/hip_runtime.h>

#define D 128
#define CAP 4096   // bucket capacity (mean 3061, sigma ~55 at E=600K -> +18 sigma)

typedef __attribute__((ext_vector_type(8))) short short8;
typedef __attribute__((ext_vector_type(4))) float f32x4;

typedef __attribute__((address_space(3))) unsigned int lds_u32_t;
typedef const __attribute__((address_space(1))) unsigned int glb_u32_t;

static __device__ __forceinline__ unsigned short f2bf(float f) {
    unsigned int u = __float_as_uint(f);
    unsigned int r = (u + 0x7fffu + ((u >> 16) & 1u)) >> 16;
    return (unsigned short)r;
}
static __device__ __forceinline__ float bf_lo(unsigned int u) {
    return __uint_as_float(u << 16);
}
static __device__ __forceinline__ float bf_hi(unsigned int u) {
    return __uint_as_float(u & 0xffff0000u);
}
static __device__ __forceinline__ unsigned int pack2(float lo, float hi) {
    return (unsigned int)f2bf(lo) | ((unsigned int)f2bf(hi) << 16);
}
// weighted accumulate (bf16 pair-packed input): w=0 nullifies dummy gathers
static __device__ __forceinline__ void acc8w(float* acc, uint4 v, float w) {
    acc[0] = fmaf(bf_lo(v.x), w, acc[0]); acc[1] = fmaf(bf_hi(v.x), w, acc[1]);
    acc[2] = fmaf(bf_lo(v.y), w, acc[2]); acc[3] = fmaf(bf_hi(v.y), w, acc[3]);
    acc[4] = fmaf(bf_lo(v.z), w, acc[4]); acc[5] = fmaf(bf_hi(v.z), w, acc[5]);
    acc[6] = fmaf(bf_lo(v.w), w, acc[6]); acc[7] = fmaf(bf_hi(v.w), w, acc[7]);
}
// weighted accumulate (fp32 input, two float4s)
static __device__ __forceinline__ void acc8f(float* acc, float4 a, float4 b, float w) {
    acc[0] = fmaf(a.x, w, acc[0]); acc[1] = fmaf(a.y, w, acc[1]);
    acc[2] = fmaf(a.z, w, acc[2]); acc[3] = fmaf(a.w, w, acc[3]);
    acc[4] = fmaf(b.x, w, acc[4]); acc[5] = fmaf(b.y, w, acc[5]);
    acc[6] = fmaf(b.z, w, acc[6]); acc[7] = fmaf(b.w, w, acc[7]);
}

// ------- prep: W convert [0,32) | bucketA (rest). No x conversion (r12 post-mortem:
// the 38MB convert pass cost ~40µs for unclear reasons; deleted, layer 1 reads fp32 x).
// bucket_cnt must be zeroed (1 KB hipMemsetAsync) before this kernel.

__global__ void prep_kernel(const float* __restrict__ W0, const float* __restrict__ W1,
                            const float* __restrict__ W2, const float* __restrict__ W3,
                            unsigned short* __restrict__ wt,
                            const int* __restrict__ src, const int* __restrict__ dst,
                            int* __restrict__ bucket_cnt, unsigned int* __restrict__ bucket_buf,
                            int E) {
    int bx = blockIdx.x;
    int t = threadIdx.x;
    if (bx < 32) {
        // W [128k][128n] fp32 -> wt bf16 [m][n][chunk-swizzled k]: chunk c at slot c ^ (n&15)
        int tid = bx * 256 + t;            // 0..8191
        int m = tid >> 11;
        const float* W = (m == 0) ? W0 : (m == 1) ? W1 : (m == 2) ? W2 : W3;
        int r = tid & 2047;
        int n = r >> 4;
        int c = r & 15;
        float f[8];
#pragma unroll
        for (int i = 0; i < 8; ++i) f[i] = W[(size_t)(c * 8 + i) * 128 + n];
        uint4 o;
        o.x = pack2(f[0], f[1]);
        o.y = pack2(f[2], f[3]);
        o.z = pack2(f[4], f[5]);
        o.w = pack2(f[6], f[7]);
        *reinterpret_cast<uint4*>(wt + (size_t)m * 16384 + n * 128 + (c ^ (n & 15)) * 8) = o;
    } else {
        // bucketA: bin edges by dst>>8. LDS histogram -> one global reservation per
        // bucket -> scatter packed (dstlocal<<24 | src) into bucket regions.
        __shared__ int hist[256];
        __shared__ int cur[256];
        hist[t] = 0;
        __syncthreads();
        int base = (bx - 32) * 4096;
#pragma unroll
        for (int i = 0; i < 16; ++i) {
            int e = base + t + i * 256;
            if (e < E) atomicAdd(&hist[dst[e] >> 8], 1);
        }
        __syncthreads();
        if (hist[t] > 0) cur[t] = atomicAdd(&bucket_cnt[t], hist[t]);
        __syncthreads();
#pragma unroll
        for (int i = 0; i < 16; ++i) {
            int e = base + t + i * 256;
            if (e < E) {
                int d = dst[e];
                int s = src[e];
                int b = d >> 8;
                int pos = atomicAdd(&cur[b], 1);
                bucket_buf[(size_t)b * CAP + pos] = ((unsigned)(d & 255) << 24) | (unsigned)s;
            }
        }
    }
}

// Pass B: one block per bucket. Node histogram in LDS -> scan -> rowptr (coalesced) +
// scatter src into the bucket's CSR segment (~12 KB window, line-local).

__global__ void bucketB_kernel(const int* __restrict__ bucket_cnt,
                               const unsigned int* __restrict__ bucket_buf,
                               int* __restrict__ rowptr, int* __restrict__ ssrc,
                               int N, int E, int nbkt) {
    __shared__ int pref[256];
    __shared__ int lsc[256];
    int b = blockIdx.x;
    int t = threadIdx.x;
    // inclusive scan of bucket sizes (every block does the same tiny scan)
    pref[t] = (t < nbkt) ? bucket_cnt[t] : 0;
    __syncthreads();
    for (int off = 1; off < 256; off <<= 1) {
        int u = (t >= off) ? pref[t - off] : 0;
        __syncthreads();
        pref[t] += u;
        __syncthreads();
    }
    int cnt_b = bucket_cnt[b];
    int base_b = pref[b] - cnt_b;      // exclusive global base of this bucket
    // local node histogram
    lsc[t] = 0;
    __syncthreads();
    for (int i = t; i < cnt_b; i += 256)
        atomicAdd(&lsc[bucket_buf[(size_t)b * CAP + i] >> 24], 1);
    __syncthreads();
    int c = lsc[t];
    __syncthreads();
    // inclusive scan of node counts
    for (int off = 1; off < 256; off <<= 1) {
        int u = (t >= off) ? lsc[t - off] : 0;
        __syncthreads();
        lsc[t] += u;
        __syncthreads();
    }
    int mybase = base_b + lsc[t] - c;   // exclusive global start for node b*256+t
    int node = b * 256 + t;
    if (node < N) rowptr[node] = mybase;
    if (b == nbkt - 1 && t == 0) rowptr[N] = E;
    __syncthreads();
    lsc[t] = mybase;                    // reuse as global cursor
    __syncthreads();
    for (int i = t; i < cnt_b; i += 256) {
        unsigned v = bucket_buf[(size_t)b * CAP + i];
        int pos = atomicAdd(&lsc[v >> 24], 1);
        ssrc[pos] = (int)(v & 0xFFFFFFu);
    }
}

// ---------------- mean aggregation (fp32 OR bf16 in, bf16 out, fp32 accum) ----------------
// one wave per node (fresh-wave TLP beats grid-stride: r11 post-mortem). ONE coalesced
// wave-wide index load, then windows of 16 edges with wave-uniform trip counts (all 64
// lanes active at every __shfl — r7 lesson); quarter-wave q gathers 4 independent rows;
// invalid slots gather row 0 with fma weight 0.

template <bool IN_F32>
__global__ void agg_kernel(const void* __restrict__ featv, const int* __restrict__ rowptr,
                           const int* __restrict__ ssrc, unsigned short* __restrict__ out, int N) {
    const unsigned short* featb = (const unsigned short*)featv;
    const float* featf = (const float*)featv;
    int node = (blockIdx.x * blockDim.x + threadIdx.x) >> 6;
    if (node >= N) return;               // wave-uniform
    int lane = threadIdx.x & 63;
    int q = lane >> 4;
    int l15 = lane & 15;
    int beg = rowptr[node], end = rowptr[node + 1];
    int deg = end - beg;
    float acc[8] = {0.f, 0.f, 0.f, 0.f, 0.f, 0.f, 0.f, 0.f};
    for (int base = 0; base < deg; base += 64) {
        int m = deg - base;
        if (m > 64) m = 64;              // wave-uniform window size
        int sidx = 0;
        if (lane < m) sidx = ssrc[beg + base + lane];   // one coalesced load
        for (int j = 0; j < m; j += 16) {               // uniform bound: shfl always full-wave
            int e0 = j + q, e1 = j + 4 + q, e2 = j + 8 + q, e3 = j + 12 + q;
            int s0 = __shfl(sidx, e0);
            int s1 = __shfl(sidx, e1);
            int s2 = __shfl(sidx, e2);
            int s3 = __shfl(sidx, e3);
            float w0 = (e0 < m) ? 1.f : 0.f;
            float w1 = (e1 < m) ? 1.f : 0.f;
            float w2 = (e2 < m) ? 1.f : 0.f;
            float w3 = (e3 < m) ? 1.f : 0.f;
            if (e0 >= m) s0 = 0;         // safe row; weight 0 nullifies
            if (e1 >= m) s1 = 0;
            if (e2 >= m) s2 = 0;
            if (e3 >= m) s3 = 0;
            if (IN_F32) {
                const float* p0 = featf + (size_t)s0 * D + l15 * 8;
                const float* p1 = featf + (size_t)s1 * D + l15 * 8;
                const float* p2 = featf + (size_t)s2 * D + l15 * 8;
                const float* p3 = featf + (size_t)s3 * D + l15 * 8;
                float4 a0 = *reinterpret_cast<const float4*>(p0);
                float4 b0 = *reinterpret_cast<const float4*>(p0 + 4);
                float4 a1 = *reinterpret_cast<const float4*>(p1);
                float4 b1 = *reinterpret_cast<const float4*>(p1 + 4);
                float4 a2 = *reinterpret_cast<const float4*>(p2);
                float4 b2 = *reinterpret_cast<const float4*>(p2 + 4);
                float4 a3 = *reinterpret_cast<const float4*>(p3);
                float4 b3 = *reinterpret_cast<const float4*>(p3 + 4);
                acc8f(acc, a0, b0, w0);
                acc8f(acc, a1, b1, w1);
                acc8f(acc, a2, b2, w2);
                acc8f(acc, a3, b3, w3);
            } else {
                uint4 v0 = *reinterpret_cast<const uint4*>(featb + (size_t)s0 * D + l15 * 8);
                uint4 v1 = *reinterpret_cast<const uint4*>(featb + (size_t)s1 * D + l15 * 8);
                uint4 v2 = *reinterpret_cast<const uint4*>(featb + (size_t)s2 * D + l15 * 8);
                uint4 v3 = *reinterpret_cast<const uint4*>(featb + (size_t)s3 * D + l15 * 8);
                acc8w(acc, v0, w0);
                acc8w(acc, v1, w1);
                acc8w(acc, v2, w2);
                acc8w(acc, v3, w3);
            }
        }
    }
#pragma unroll
    for (int j = 0; j < 8; ++j) {
        acc[j] += __shfl_xor(acc[j], 16);
        acc[j] += __shfl_xor(acc[j], 32);
    }
    if (lane < 16) {
        float inv = 1.0f / (float)(deg > 1 ? deg : 1);
        uint4 o;
        o.x = pack2(acc[0] * inv, acc[1] * inv);
        o.y = pack2(acc[2] * inv, acc[3] * inv);
        o.z = pack2(acc[4] * inv, acc[5] * inv);
        o.w = pack2(acc[6] * inv, acc[7] * inv);
        *reinterpret_cast<uint4*>(out + (size_t)node * D + l15 * 8) = o;
    }
}

// ---------------- MFMA dual-GEMM: out = A1*Wt[0] + A2*Wt[1] + bias [, relu] ----------------
// block: 256 thr / 4 waves; tile 128 rows x 128 cols; wave = 32 rows (M_rep=2) x 128 cols.
// No A staging (each A row consumed by exactly one block). Both W passes in 64 KB LDS. ONE
// barrier. A2 may be fp32 (layer 1 reads x directly; rows>=N clamped to 0 — exact-size input).

template <bool RELU, bool OUT_BF16, bool A2_F32>
__global__ __launch_bounds__(256)
void gemm_mfma_kernel(const unsigned short* __restrict__ A1, const void* __restrict__ A2v,
                      const unsigned short* __restrict__ Wt,   // [2][128n][128k-swz] bf16
                      const float* __restrict__ bias, void* __restrict__ outp, int N) {
    __shared__ unsigned short Wlds[2][128 * 128];   // 64 KB, swizzle baked in global layout

    const int t = threadIdx.x;
    const int w = t >> 6;
    const int lane = t & 63;
    const int l15 = lane & 15;
    const int g = lane >> 4;
    const size_t row0 = (size_t)blockIdx.x * 128;

#pragma unroll
    for (int i = 0; i < 16; ++i) {
        int d = t + 256 * i;    // short8 index 0..4095
        __builtin_amdgcn_global_load_lds((glb_u32_t*)(Wt + (size_t)d * 8),
                                         (lds_u32_t*)(&Wlds[0][0] + (size_t)d * 8), 16, 0, 0);
    }

    // preload all A fragments (A1: padded workspace; A2 fp32: clamp rows >= N)
    short8 a[2][2][4];   // [pass][row-group][kiter]
#pragma unroll
    for (int ps = 0; ps < 2; ++ps) {
#pragma unroll
        for (int m = 0; m < 2; ++m) {
            size_t r = row0 + w * 32 + m * 16 + l15;
            if (ps == 0) {
#pragma unroll
                for (int k = 0; k < 4; ++k)
                    a[0][m][k] = *reinterpret_cast<const short8*>(A1 + r * D + (k * 4 + g) * 8);
            } else if (A2_F32) {
                const float* Af = (const float*)A2v;
                size_t rr = (r < (size_t)N) ? r : 0;
#pragma unroll
                for (int k = 0; k < 4; ++k) {
                    const float* p = Af + rr * D + (k * 4 + g) * 8;
                    float4 f0 = *reinterpret_cast<const float4*>(p);
                    float4 f1 = *reinterpret_cast<const float4*>(p + 4);
                    uint4 u;
                    u.x = pack2(f0.x, f0.y);
                    u.y = pack2(f0.z, f0.w);
                    u.z = pack2(f1.x, f1.y);
                    u.w = pack2(f1.z, f1.w);
                    a[1][m][k] = *reinterpret_cast<const short8*>(&u);
                }
            } else {
                const unsigned short* Ab = (const unsigned short*)A2v;
#pragma unroll
                for (int k = 0; k < 4; ++k)
                    a[1][m][k] = *reinterpret_cast<const short8*>(Ab + r * D + (k * 4 + g) * 8);
            }
        }
    }

    float bb[8];
#pragma unroll
    for (int j = 0; j < 8; ++j) bb[j] = bias[j * 16 + l15];

    f32x4 acc[2][8];
#pragma unroll
    for (int m = 0; m < 2; ++m)
#pragma unroll
        for (int j = 0; j < 8; ++j) acc[m][j] = (f32x4){0.f, 0.f, 0.f, 0.f};

    __syncthreads();   // drains vmcnt: W in LDS, A in regs

#pragma unroll
    for (int ps = 0; ps < 2; ++ps)
#pragma unroll
        for (int k = 0; k < 4; ++k) {
            int c = k * 4 + g;
#pragma unroll
            for (int j = 0; j < 8; ++j) {
                short8 b = *reinterpret_cast<const short8*>(
                    &Wlds[ps][(j * 16 + l15) * 128 + ((c ^ l15) * 8)]);
                acc[0][j] = __builtin_amdgcn_mfma_f32_16x16x32_bf16(a[ps][0][k], b, acc[0][j], 0, 0, 0);
                acc[1][j] = __builtin_amdgcn_mfma_f32_16x16x32_bf16(a[ps][1][k], b, acc[1][j], 0, 0, 0);
            }
        }

    // epilogue: C/D layout col=lane&15, row=(lane>>4)*4+reg
    unsigned short* outb = (unsigned short*)outp;
    float* outf = (float*)outp;
#pragma unroll
    for (int m = 0; m < 2; ++m) {
        size_t rbase = row0 + w * 32 + m * 16 + g * 4;
#pragma unroll
        for (int reg = 0; reg < 4; ++reg) {
            size_t row = rbase + reg;
            if (row < (size_t)N) {
#pragma unroll
                for (int j = 0; j < 8; ++j) {
                    float v = acc[m][j][reg] + bb[j];
                    if (RELU) v = v > 0.f ? v : 0.f;
                    if (OUT_BF16) outb[row * D + j * 16 + l15] = f2bf(v);
                    else          outf[row * D + j * 16 + l15] = v;
                }
            }
        }
    }
}

// ---------------- launch ----------------

extern "C" void kernel_launch(void* const* d_in, const int* in_sizes, int n_in,
                              void* d_out, int out_size, void* d_ws, size_t ws_size,
                              hipStream_t stream) {
    const float* x    = (const float*)d_in[0];
    const int*   eidx = (const int*)d_in[1];
    const float* W_l1 = (const float*)d_in[2];
    const float* W_r1 = (const float*)d_in[3];
    const float* b1   = (const float*)d_in[4];
    const float* W_l2 = (const float*)d_in[5];
    const float* W_r2 = (const float*)d_in[6];
    const float* b2   = (const float*)d_in[7];
    float* out = (float*)d_out;

    const int N = in_sizes[0] / D;
    const int E = in_sizes[1] / 2;
    const int N_pad = (N + 127) & ~127;
    const int nbkt = (N + 255) >> 8;    // 196 for N=50000 (must be <= 256)
    const int* src = eidx;
    const int* dst = eidx + E;

    char* ws = (char*)d_ws;
    size_t off = 0;
    auto alloc = [&](size_t bytes) {
        char* p = ws + off;
        off += (bytes + 511) & ~(size_t)511;
        return p;
    };
    int*            rowptr     = (int*)alloc((size_t)(N + 1) * 4);
    int*            bucket_cnt = (int*)alloc(1024);
    unsigned int*   bucket_buf = (unsigned int*)alloc((size_t)nbkt * CAP * 4);
    int*            ssrc       = (int*)alloc((size_t)E * 4);
    unsigned short* hb         = (unsigned short*)alloc((size_t)N_pad * D * 2);
    unsigned short* aggb       = (unsigned short*)alloc((size_t)N_pad * D * 2);
    unsigned short* wt         = (unsigned short*)alloc((size_t)4 * 128 * 128 * 2);

    const int NB_bktA = (E + 4095) / 4096;
    const int NB_prep = 32 + NB_bktA;
    const int NB_agg  = (N + 3) / 4;    // one wave per node
    const int NB_gemm = N_pad / 128;

    // W convert + bucketed CSR build
    hipMemsetAsync(bucket_cnt, 0, 1024, stream);
    prep_kernel<<<NB_prep, 256, 0, stream>>>(W_l1, W_r1, W_l2, W_r2, wt,
                                             src, dst, bucket_cnt, bucket_buf, E);
    bucketB_kernel<<<nbkt, 256, 0, stream>>>(bucket_cnt, bucket_buf, rowptr, ssrc, N, E, nbkt);

    // layer 1: agg reads fp32 x directly; gemm A2 = fp32 x (in-reg convert)
    agg_kernel<true><<<NB_agg, 256, 0, stream>>>(x, rowptr, ssrc, aggb, N);
    gemm_mfma_kernel<true, true, true><<<NB_gemm, 256, 0, stream>>>(aggb, x, wt, b1, hb, N);

    // layer 2: all bf16
    agg_kernel<false><<<NB_agg, 256, 0, stream>>>(hb, rowptr, ssrc, aggb, N);
    gemm_mfma_kernel<false, false, false><<<NB_gemm, 256, 0, stream>>>(aggb, hb, wt + 2 * 16384, b2, out, N);
}

// Round 14
// 101.964 us; speedup vs baseline: 1.1658x; 1.1658x over previous
//
#include <hip/hip_runtime.h>

#define D 128
#define CAP 4096   // bucket capacity (mean 3061, sigma ~55 at E=600K -> +18 sigma)

typedef __attribute__((ext_vector_type(8))) short short8;
typedef __attribute__((ext_vector_type(4))) float f32x4;

typedef __attribute__((address_space(3))) unsigned int lds_u32_t;
typedef const __attribute__((address_space(1))) unsigned int glb_u32_t;

static __device__ __forceinline__ unsigned short f2bf(float f) {
    unsigned int u = __float_as_uint(f);
    unsigned int r = (u + 0x7fffu + ((u >> 16) & 1u)) >> 16;
    return (unsigned short)r;
}
static __device__ __forceinline__ float bf_lo(unsigned int u) {
    return __uint_as_float(u << 16);
}
static __device__ __forceinline__ float bf_hi(unsigned int u) {
    return __uint_as_float(u & 0xffff0000u);
}
static __device__ __forceinline__ unsigned int pack2(float lo, float hi) {
    return (unsigned int)f2bf(lo) | ((unsigned int)f2bf(hi) << 16);
}
// weighted accumulate: w=0 nullifies dummy gathers (branch-free predication)
static __device__ __forceinline__ void acc8w(float* acc, uint4 v, float w) {
    acc[0] = fmaf(bf_lo(v.x), w, acc[0]); acc[1] = fmaf(bf_hi(v.x), w, acc[1]);
    acc[2] = fmaf(bf_lo(v.y), w, acc[2]); acc[3] = fmaf(bf_hi(v.y), w, acc[3]);
    acc[4] = fmaf(bf_lo(v.z), w, acc[4]); acc[5] = fmaf(bf_hi(v.z), w, acc[5]);
    acc[6] = fmaf(bf_lo(v.w), w, acc[6]); acc[7] = fmaf(bf_hi(v.w), w, acc[7]);
}

// ------- prep: W convert (blocks 0..31, block 0 zeroes bucket_cnt), x convert (rest) -------

__global__ void prep_kernel(const float* __restrict__ x, unsigned short* __restrict__ xb,
                            int total8,
                            const float* __restrict__ W0, const float* __restrict__ W1,
                            const float* __restrict__ W2, const float* __restrict__ W3,
                            unsigned short* __restrict__ wt,
                            int* __restrict__ bucket_cnt) {
    int bx = blockIdx.x;
    int t = threadIdx.x;
    if (bx == 0) bucket_cnt[t] = 0;     // 256 ints
    if (bx < 32) {
        // W [128k][128n] fp32 -> wt bf16 [m][n][chunk-swizzled k]: chunk c at slot c ^ (n&15)
        int tid = bx * 256 + t;            // 0..8191
        int m = tid >> 11;
        const float* W = (m == 0) ? W0 : (m == 1) ? W1 : (m == 2) ? W2 : W3;
        int r = tid & 2047;
        int n = r >> 4;
        int c = r & 15;
        float f[8];
#pragma unroll
        for (int i = 0; i < 8; ++i) f[i] = W[(size_t)(c * 8 + i) * 128 + n];
        uint4 o;
        o.x = pack2(f[0], f[1]);
        o.y = pack2(f[2], f[3]);
        o.z = pack2(f[4], f[5]);
        o.w = pack2(f[6], f[7]);
        *reinterpret_cast<uint4*>(wt + (size_t)m * 16384 + n * 128 + (c ^ (n & 15)) * 8) = o;
    } else {
        int i = (bx - 32) * 256 + t;
        if (i < total8) {
            const float4 v0 = *reinterpret_cast<const float4*>(x + (size_t)i * 8);
            const float4 v1 = *reinterpret_cast<const float4*>(x + (size_t)i * 8 + 4);
            uint4 o;
            o.x = pack2(v0.x, v0.y);
            o.y = pack2(v0.z, v0.w);
            o.z = pack2(v1.x, v1.y);
            o.w = pack2(v1.z, v1.w);
            *reinterpret_cast<uint4*>(xb + (size_t)i * 8) = o;
        }
    }
}

// ---------------- bucketed CSR build ----------------
// Pass A: bin edges by dst>>8. Per block: LDS histogram -> one global reservation per
// bucket -> scatter packed (dstlocal<<24 | src) into bucket regions.

__global__ void bucketA_kernel(const int* __restrict__ src, const int* __restrict__ dst,
                               int* __restrict__ bucket_cnt, unsigned int* __restrict__ bucket_buf,
                               int E) {
    __shared__ int hist[256];
    __shared__ int cur[256];
    int t = threadIdx.x;
    hist[t] = 0;
    __syncthreads();
    int base = blockIdx.x * 4096;
#pragma unroll
    for (int i = 0; i < 16; ++i) {
        int e = base + t + i * 256;
        if (e < E) atomicAdd(&hist[dst[e] >> 8], 1);
    }
    __syncthreads();
    if (hist[t] > 0) cur[t] = atomicAdd(&bucket_cnt[t], hist[t]);
    __syncthreads();
#pragma unroll
    for (int i = 0; i < 16; ++i) {
        int e = base + t + i * 256;
        if (e < E) {
            int d = dst[e];
            int s = src[e];
            int b = d >> 8;
            int pos = atomicAdd(&cur[b], 1);
            bucket_buf[(size_t)b * CAP + pos] = ((unsigned)(d & 255) << 24) | (unsigned)s;
        }
    }
}

// Pass B: one block per bucket. Node histogram in LDS -> scan -> rowptr (coalesced) +
// scatter src into the bucket's CSR segment (~12 KB window, line-local).

__global__ void bucketB_kernel(const int* __restrict__ bucket_cnt,
                               const unsigned int* __restrict__ bucket_buf,
                               int* __restrict__ rowptr, int* __restrict__ ssrc,
                               int N, int E, int nbkt) {
    __shared__ int pref[256];
    __shared__ int lsc[256];
    int b = blockIdx.x;
    int t = threadIdx.x;
    // inclusive scan of bucket sizes (every block does the same tiny scan)
    pref[t] = (t < nbkt) ? bucket_cnt[t] : 0;
    __syncthreads();
    for (int off = 1; off < 256; off <<= 1) {
        int u = (t >= off) ? pref[t - off] : 0;
        __syncthreads();
        pref[t] += u;
        __syncthreads();
    }
    int cnt_b = bucket_cnt[b];
    int base_b = pref[b] - cnt_b;      // exclusive global base of this bucket
    // local node histogram
    lsc[t] = 0;
    __syncthreads();
    for (int i = t; i < cnt_b; i += 256)
        atomicAdd(&lsc[bucket_buf[(size_t)b * CAP + i] >> 24], 1);
    __syncthreads();
    int c = lsc[t];
    __syncthreads();
    // inclusive scan of node counts
    for (int off = 1; off < 256; off <<= 1) {
        int u = (t >= off) ? lsc[t - off] : 0;
        __syncthreads();
        lsc[t] += u;
        __syncthreads();
    }
    int mybase = base_b + lsc[t] - c;   // exclusive global start for node b*256+t
    int node = b * 256 + t;
    if (node < N) rowptr[node] = mybase;
    if (b == nbkt - 1 && t == 0) rowptr[N] = E;
    __syncthreads();
    lsc[t] = mybase;                    // reuse as global cursor
    __syncthreads();
    for (int i = t; i < cnt_b; i += 256) {
        unsigned v = bucket_buf[(size_t)b * CAP + i];
        int pos = atomicAdd(&lsc[v >> 24], 1);
        ssrc[pos] = (int)(v & 0xFFFFFFu);
    }
}

// ---------------- mean aggregation (bf16 in, bf16 out, fp32 accum) ----------------
// one wave per node (fresh-wave TLP beats grid-stride: r11 post-mortem). ONE coalesced
// wave-wide index load, then windows of 16 edges with wave-uniform trip counts (all 64
// lanes active at every __shfl — r7 lesson); quarter-wave q gathers 4 independent 256B
// rows; invalid slots gather row 0 with fma weight 0.

__global__ void agg_kernel(const unsigned short* __restrict__ feat, const int* __restrict__ rowptr,
                           const int* __restrict__ ssrc, unsigned short* __restrict__ out, int N) {
    int node = (blockIdx.x * blockDim.x + threadIdx.x) >> 6;
    if (node >= N) return;               // wave-uniform
    int lane = threadIdx.x & 63;
    int q = lane >> 4;
    int l15 = lane & 15;
    int beg = rowptr[node], end = rowptr[node + 1];
    int deg = end - beg;
    float acc[8] = {0.f, 0.f, 0.f, 0.f, 0.f, 0.f, 0.f, 0.f};
    for (int base = 0; base < deg; base += 64) {
        int m = deg - base;
        if (m > 64) m = 64;              // wave-uniform window size
        int sidx = 0;
        if (lane < m) sidx = ssrc[beg + base + lane];   // one coalesced load
        for (int j = 0; j < m; j += 16) {               // uniform bound: shfl always full-wave
            int e0 = j + q, e1 = j + 4 + q, e2 = j + 8 + q, e3 = j + 12 + q;
            int s0 = __shfl(sidx, e0);
            int s1 = __shfl(sidx, e1);
            int s2 = __shfl(sidx, e2);
            int s3 = __shfl(sidx, e3);
            float w0 = (e0 < m) ? 1.f : 0.f;
            float w1 = (e1 < m) ? 1.f : 0.f;
            float w2 = (e2 < m) ? 1.f : 0.f;
            float w3 = (e3 < m) ? 1.f : 0.f;
            if (e0 >= m) s0 = 0;         // safe row; weight 0 nullifies
            if (e1 >= m) s1 = 0;
            if (e2 >= m) s2 = 0;
            if (e3 >= m) s3 = 0;
            uint4 v0 = *reinterpret_cast<const uint4*>(feat + (size_t)s0 * D + l15 * 8);
            uint4 v1 = *reinterpret_cast<const uint4*>(feat + (size_t)s1 * D + l15 * 8);
            uint4 v2 = *reinterpret_cast<const uint4*>(feat + (size_t)s2 * D + l15 * 8);
            uint4 v3 = *reinterpret_cast<const uint4*>(feat + (size_t)s3 * D + l15 * 8);
            acc8w(acc, v0, w0);
            acc8w(acc, v1, w1);
            acc8w(acc, v2, w2);
            acc8w(acc, v3, w3);
        }
    }
#pragma unroll
    for (int j = 0; j < 8; ++j) {
        acc[j] += __shfl_xor(acc[j], 16);
        acc[j] += __shfl_xor(acc[j], 32);
    }
    if (lane < 16) {
        float inv = 1.0f / (float)(deg > 1 ? deg : 1);
        uint4 o;
        o.x = pack2(acc[0] * inv, acc[1] * inv);
        o.y = pack2(acc[2] * inv, acc[3] * inv);
        o.z = pack2(acc[4] * inv, acc[5] * inv);
        o.w = pack2(acc[6] * inv, acc[7] * inv);
        *reinterpret_cast<uint4*>(out + (size_t)node * D + l15 * 8) = o;
    }
}

// ---------------- MFMA dual-GEMM: out = A1*Wt[0] + A2*Wt[1] + bias [, relu] ----------------
// block: 256 thr / 4 waves; tile 128 rows x 128 cols; wave = 32 rows (M_rep=2) x 128 cols.
// No A staging (each A row consumed by exactly one block). Both W passes in 64 KB LDS. ONE barrier.

template <bool RELU, bool OUT_BF16>
__global__ __launch_bounds__(256)
void gemm_mfma_kernel(const unsigned short* __restrict__ A1, const unsigned short* __restrict__ A2,
                      const unsigned short* __restrict__ Wt,   // [2][128n][128k-swz] bf16
                      const float* __restrict__ bias, void* __restrict__ outp, int N) {
    __shared__ unsigned short Wlds[2][128 * 128];   // 64 KB, swizzle baked in global layout

    const int t = threadIdx.x;
    const int w = t >> 6;
    const int lane = t & 63;
    const int l15 = lane & 15;
    const int g = lane >> 4;
    const size_t row0 = (size_t)blockIdx.x * 128;

#pragma unroll
    for (int i = 0; i < 16; ++i) {
        int d = t + 256 * i;    // short8 index 0..4095
        __builtin_amdgcn_global_load_lds((glb_u32_t*)(Wt + (size_t)d * 8),
                                         (lds_u32_t*)(&Wlds[0][0] + (size_t)d * 8), 16, 0, 0);
    }

    // preload all A fragments direct from global (rows >= N read junk; outputs dropped)
    short8 a[2][2][4];   // [pass][row-group][kiter]
#pragma unroll
    for (int p = 0; p < 2; ++p) {
        const unsigned short* __restrict__ Ap = p ? A2 : A1;
#pragma unroll
        for (int m = 0; m < 2; ++m) {
            size_t r = row0 + w * 32 + m * 16 + l15;
#pragma unroll
            for (int k = 0; k < 4; ++k)
                a[p][m][k] = *reinterpret_cast<const short8*>(Ap + r * D + (k * 4 + g) * 8);
        }
    }

    float bb[8];
#pragma unroll
    for (int j = 0; j < 8; ++j) bb[j] = bias[j * 16 + l15];

    f32x4 acc[2][8];
#pragma unroll
    for (int m = 0; m < 2; ++m)
#pragma unroll
        for (int j = 0; j < 8; ++j) acc[m][j] = (f32x4){0.f, 0.f, 0.f, 0.f};

    __syncthreads();   // drains vmcnt: W in LDS, A in regs

#pragma unroll
    for (int p = 0; p < 2; ++p)
#pragma unroll
        for (int k = 0; k < 4; ++k) {
            int c = k * 4 + g;
#pragma unroll
            for (int j = 0; j < 8; ++j) {
                short8 b = *reinterpret_cast<const short8*>(
                    &Wlds[p][(j * 16 + l15) * 128 + ((c ^ l15) * 8)]);
                acc[0][j] = __builtin_amdgcn_mfma_f32_16x16x32_bf16(a[p][0][k], b, acc[0][j], 0, 0, 0);
                acc[1][j] = __builtin_amdgcn_mfma_f32_16x16x32_bf16(a[p][1][k], b, acc[1][j], 0, 0, 0);
            }
        }

    // epilogue: C/D layout col=lane&15, row=(lane>>4)*4+reg
    unsigned short* outb = (unsigned short*)outp;
    float* outf = (float*)outp;
#pragma unroll
    for (int m = 0; m < 2; ++m) {
        size_t rbase = row0 + w * 32 + m * 16 + g * 4;
#pragma unroll
        for (int reg = 0; reg < 4; ++reg) {
            size_t row = rbase + reg;
            if (row < (size_t)N) {
#pragma unroll
                for (int j = 0; j < 8; ++j) {
                    float v = acc[m][j][reg] + bb[j];
                    if (RELU) v = v > 0.f ? v : 0.f;
                    if (OUT_BF16) outb[row * D + j * 16 + l15] = f2bf(v);
                    else          outf[row * D + j * 16 + l15] = v;
                }
            }
        }
    }
}

// ---------------- launch ----------------

extern "C" void kernel_launch(void* const* d_in, const int* in_sizes, int n_in,
                              void* d_out, int out_size, void* d_ws, size_t ws_size,
                              hipStream_t stream) {
    const float* x    = (const float*)d_in[0];
    const int*   eidx = (const int*)d_in[1];
    const float* W_l1 = (const float*)d_in[2];
    const float* W_r1 = (const float*)d_in[3];
    const float* b1   = (const float*)d_in[4];
    const float* W_l2 = (const float*)d_in[5];
    const float* W_r2 = (const float*)d_in[6];
    const float* b2   = (const float*)d_in[7];
    float* out = (float*)d_out;

    const int N = in_sizes[0] / D;
    const int E = in_sizes[1] / 2;
    const int N_pad = (N + 127) & ~127;
    const int nbkt = (N + 255) >> 8;    // 196 for N=50000 (must be <= 256)
    const int* src = eidx;
    const int* dst = eidx + E;

    char* ws = (char*)d_ws;
    size_t off = 0;
    auto alloc = [&](size_t bytes) {
        char* p = ws + off;
        off += (bytes + 511) & ~(size_t)511;
        return p;
    };
    int*            rowptr     = (int*)alloc((size_t)(N + 1) * 4);
    int*            bucket_cnt = (int*)alloc(1024);
    unsigned int*   bucket_buf = (unsigned int*)alloc((size_t)nbkt * CAP * 4);
    int*            ssrc       = (int*)alloc((size_t)E * 4);
    unsigned short* xb         = (unsigned short*)alloc((size_t)N_pad * D * 2);
    unsigned short* hb         = (unsigned short*)alloc((size_t)N_pad * D * 2);
    unsigned short* aggb       = (unsigned short*)alloc((size_t)N_pad * D * 2);
    unsigned short* wt         = (unsigned short*)alloc((size_t)4 * 128 * 128 * 2);

    const int total8    = N * D / 8;
    const int xb_blocks = (total8 + 255) / 256;
    const int NB_prep   = 32 + xb_blocks;
    const int NB_bktA   = (E + 4095) / 4096;
    const int NB_agg    = (N + 3) / 4;
    const int NB_gemm   = N_pad / 128;

    // conversions + bucketed CSR build
    prep_kernel<<<NB_prep, 256, 0, stream>>>(x, xb, total8, W_l1, W_r1, W_l2, W_r2, wt, bucket_cnt);
    bucketA_kernel<<<NB_bktA, 256, 0, stream>>>(src, dst, bucket_cnt, bucket_buf, E);
    bucketB_kernel<<<nbkt, 256, 0, stream>>>(bucket_cnt, bucket_buf, rowptr, ssrc, N, E, nbkt);

    // layer 1
    agg_kernel<<<NB_agg, 256, 0, stream>>>(xb, rowptr, ssrc, aggb, N);
    gemm_mfma_kernel<true, true><<<NB_gemm, 256, 0, stream>>>(aggb, xb, wt, b1, hb, N);

    // layer 2
    agg_kernel<<<NB_agg, 256, 0, stream>>>(hb, rowptr, ssrc, aggb, N);
    gemm_mfma_kernel<false, false><<<NB_gemm, 256, 0, stream>>>(aggb, hb, wt + 2 * 16384, b2, out, N);
}